// Round 6
// baseline (333.267 us; speedup 1.0000x reference)
//
#include <hip/hip_runtime.h>

// Shapes: B=32, S_NEW=1, DIM=4096, H=32, KV=8, HD=128, PREV=2048, SEQ=2049
// All inputs/outputs fp32.
//
// ws layout (float offsets):
//   P1   [16][32][6144] @ 0        (3145728) qkv split-K partials
//   PA   [1024][520]    @ 0        (532480)  flash partials (ALIASES dead P1)
//   qkv  [32][6144]     @ 3145728  (196608)  rope'd q (scaled), k_new, v_new
//   attn [32][4096]     @ 3342336  (131072)  attention output (b, h, d)
//   P2   [16][32][4096] @ 3473408  (2097152) out-proj split-K partials

#define WS_P1   0
#define WS_PA   0
#define WS_QKV  3145728
#define WS_ATTN 3342336
#define WS_P2   3473408

// ---------------------------------------------------------------------------
// Skinny GEMM partial: P[ks][b][n] = sum_{k in 256-chunk} X[b][k] * W[k][n]
// grid: (Ntot/128, 16), block: 256 = 4 k-subgroups x 64 lanes (2 cols each).
// Each kk is processed by exactly ONE wave (minimizes LDS broadcast instrs).
// ---------------------------------------------------------------------------
__global__ __launch_bounds__(256) void gemm_skinny(
    const float* __restrict__ X,
    const float* __restrict__ W0, int e0, int ld0,
    const float* __restrict__ W1, int e1, int ld1,
    const float* __restrict__ W2, int ld2,
    float* __restrict__ P, int Ntot)
{
    __shared__ float x_t[256][33];   // 33.8 KB; aliased as red[] in epilogue

    const int nb = blockIdx.x * 128;
    const float* W; int ld, noff;
    if (nb < e0)      { W = W0; ld = ld0; noff = 0;  }
    else if (nb < e1) { W = W1; ld = ld1; noff = e0; }
    else              { W = W2; ld = ld2; noff = e1; }

    const int k0  = blockIdx.y * 256;
    const int tid = threadIdx.x;
    const int cp  = tid & 63;       // col pair 0..63
    const int kg  = tid >> 6;       // k-subgroup 0..3 (one wave each)
    const int nn  = nb - noff + cp * 2;

    // stage x[32][256] transposed, coalesced reads, pad-33 conflict-free write
    #pragma unroll
    for (int i = 0; i < 32; ++i) {
        int idx = tid + i * 256;
        int bb = idx >> 8, kk = idx & 255;
        x_t[kk][bb] = X[(size_t)bb * 4096 + k0 + kk];
    }
    __syncthreads();

    float2 acc[32];
    #pragma unroll
    for (int b = 0; b < 32; ++b) { acc[b].x = 0.f; acc[b].y = 0.f; }

    const float* Wp = W + (size_t)k0 * ld + nn;
    for (int kk0 = kg * 64; kk0 < kg * 64 + 64; kk0 += 8) {
        float2 w[8];
        #pragma unroll
        for (int u = 0; u < 8; ++u)
            w[u] = *(const float2*)&Wp[(size_t)(kk0 + u) * ld];
        #pragma unroll
        for (int u = 0; u < 8; ++u) {
            const float* xr = x_t[kk0 + u];
            #pragma unroll
            for (int bq = 0; bq < 8; ++bq) {
                float4 xv = *(const float4*)&xr[bq * 4];
                acc[bq*4+0].x += xv.x * w[u].x; acc[bq*4+0].y += xv.x * w[u].y;
                acc[bq*4+1].x += xv.y * w[u].x; acc[bq*4+1].y += xv.y * w[u].y;
                acc[bq*4+2].x += xv.z * w[u].x; acc[bq*4+2].y += xv.z * w[u].y;
                acc[bq*4+3].x += xv.w * w[u].x; acc[bq*4+3].y += xv.w * w[u].y;
            }
        }
    }
    __syncthreads();   // x_t dead; alias as red[2][64][33] float2

    float2* red = (float2*)&x_t[0][0];
    if (kg >= 2) {
        float2* dst = red + (size_t)(kg - 2) * (64 * 33) + cp * 33;
        #pragma unroll
        for (int b = 0; b < 32; ++b) dst[b] = acc[b];
    }
    __syncthreads();
    if (kg < 2) {
        const float2* src = red + (size_t)kg * (64 * 33) + cp * 33;
        #pragma unroll
        for (int b = 0; b < 32; ++b) {
            acc[b].x += src[b].x; acc[b].y += src[b].y;
        }
    }
    __syncthreads();
    if (kg == 1) {
        float2* dst = red + cp * 33;
        #pragma unroll
        for (int b = 0; b < 32; ++b) dst[b] = acc[b];
    }
    __syncthreads();
    if (kg == 0) {
        const int ks = blockIdx.y;
        const float2* src = red + cp * 33;
        #pragma unroll
        for (int b = 0; b < 32; ++b) {
            float2 v; v.x = acc[b].x + src[b].x; v.y = acc[b].y + src[b].y;
            *(float2*)&P[((size_t)ks * 32 + b) * Ntot + nb + cp * 2] = v;
        }
    }
}

// ---------------------------------------------------------------------------
// Reduce 16 split-K partials for QKV + fused RoPE (+ 1/sqrt(128) on q).
// ---------------------------------------------------------------------------
__global__ __launch_bounds__(128) void reduce_rope(
    const float* __restrict__ P, const float* __restrict__ freqs,
    float* __restrict__ qkv)
{
    int t = blockIdx.x * 128 + threadIdx.x;   // 0..98303
    int b = t / 3072;
    int cp = t - b * 3072;
    int n = cp * 2;
    float sx = 0.f, sy = 0.f;
    #pragma unroll
    for (int ks = 0; ks < 16; ++ks) {
        float2 v = *(const float2*)&P[((size_t)ks * 32 + b) * 6144 + n];
        sx += v.x; sy += v.y;
    }
    if (n < 5120) {
        int d = n & 127;
        float fr = freqs[d >> 1];
        float c = cosf(fr), s = sinf(fr);
        float ra = sx * c - sy * s;
        float rb = sx * s + sy * c;
        if (n < 4096) {
            const float sc = 0.08838834764831845f;  // 1/sqrt(128)
            ra *= sc; rb *= sc;
        }
        sx = ra; sy = rb;
    }
    float2 o; o.x = sx; o.y = sy;
    *(float2*)&qkv[(size_t)b * 6144 + n] = o;
}

// ---------------------------------------------------------------------------
// Flash-decode split-S attention (round-4 version, verbatim).
// grid 1024 = (b, kv, chunk c of 512 rows), block 256 (4 waves).
// ---------------------------------------------------------------------------
__global__ __launch_bounds__(256, 4) void attn_split(
    const float* __restrict__ qkv,
    const float* __restrict__ ck, const float* __restrict__ cv,
    float* __restrict__ pa)
{
    __shared__ float sbuf[4096];   // sc[4][520] (2080) then op[8][512] (4096)
    __shared__ float pm[4], pl[4];

    const int blk = blockIdx.x;
    const int c   = blk & 3;
    const int kv  = (blk >> 2) & 7;
    const int b   = blk >> 5;
    const int tid = threadIdx.x;
    const int wave = tid >> 6, lane = tid & 63;
    const int psub = (lane >> 4) & 3, dl = lane & 15;
    const int s0 = c * 512;

    float q[4][8];
    {
        const float* qb = qkv + (size_t)b * 6144 + kv * 512 + dl * 8;
        #pragma unroll
        for (int h = 0; h < 4; ++h) {
            float4 a = *(const float4*)&qb[h * 128];
            float4 e = *(const float4*)&qb[h * 128 + 4];
            q[h][0]=a.x; q[h][1]=a.y; q[h][2]=a.z; q[h][3]=a.w;
            q[h][4]=e.x; q[h][5]=e.y; q[h][6]=e.z; q[h][7]=e.w;
        }
    }

    if (c == 3 && tid < 16) {
        const float* kr = qkv + (size_t)b * 6144 + 4096 + kv * 128 + dl * 8;
        float4 k0 = *(const float4*)kr;
        float4 k1 = *(const float4*)(kr + 4);
        float p[4];
        #pragma unroll
        for (int h = 0; h < 4; ++h) {
            p[h] = q[h][0]*k0.x + q[h][1]*k0.y + q[h][2]*k0.z + q[h][3]*k0.w
                 + q[h][4]*k1.x + q[h][5]*k1.y + q[h][6]*k1.z + q[h][7]*k1.w;
        }
        #pragma unroll
        for (int off = 1; off < 16; off <<= 1) {
            #pragma unroll
            for (int h = 0; h < 4; ++h) p[h] += __shfl_xor(p[h], off);
        }
        if (dl == 0) {
            #pragma unroll
            for (int h = 0; h < 4; ++h) sbuf[h * 520 + 512] = p[h];
        }
    }

    const float* kbase = ck + ((size_t)b * 2048 * 8 + kv) * 128
                            + (size_t)s0 * 1024;
    const int srow = wave * 4 + psub;       // 0..15
    for (int it0 = 0; it0 < 32; it0 += 4) {
        float4 kA[4][2];
        #pragma unroll
        for (int u = 0; u < 4; ++u) {
            const float* kr = kbase + (size_t)((it0 + u) * 16 + srow) * 1024 + dl * 8;
            kA[u][0] = *(const float4*)kr;
            kA[u][1] = *(const float4*)(kr + 4);
        }
        #pragma unroll
        for (int u = 0; u < 4; ++u) {
            int s = (it0 + u) * 16 + srow;
            float p[4];
            #pragma unroll
            for (int h = 0; h < 4; ++h) {
                p[h] = q[h][0]*kA[u][0].x + q[h][1]*kA[u][0].y
                     + q[h][2]*kA[u][0].z + q[h][3]*kA[u][0].w
                     + q[h][4]*kA[u][1].x + q[h][5]*kA[u][1].y
                     + q[h][6]*kA[u][1].z + q[h][7]*kA[u][1].w;
            }
            #pragma unroll
            for (int off = 1; off < 16; off <<= 1) {
                #pragma unroll
                for (int h = 0; h < 4; ++h) p[h] += __shfl_xor(p[h], off);
            }
            if (dl == 0) {
                #pragma unroll
                for (int h = 0; h < 4; ++h) sbuf[h * 520 + s] = p[h];
            }
        }
    }
    __syncthreads();

    {
        const int h = wave;
        const int nrow = (c == 3) ? 513 : 512;
        float m = -1e30f;
        for (int s = lane; s < nrow; s += 64) m = fmaxf(m, sbuf[h * 520 + s]);
        #pragma unroll
        for (int off = 1; off < 64; off <<= 1) m = fmaxf(m, __shfl_xor(m, off));
        float sum = 0.f;
        for (int s = lane; s < nrow; s += 64) {
            float p = __expf(sbuf[h * 520 + s] - m);
            sbuf[h * 520 + s] = p;
            sum += p;
        }
        #pragma unroll
        for (int off = 1; off < 64; off <<= 1) sum += __shfl_xor(sum, off);
        if (lane == 0) { pm[h] = m; pl[h] = sum; }
    }
    __syncthreads();

    const int grp = tid >> 5, l32 = tid & 31, d4 = l32 * 4;
    float4 acc[4];
    #pragma unroll
    for (int hh = 0; hh < 4; ++hh) { acc[hh].x=0.f; acc[hh].y=0.f; acc[hh].z=0.f; acc[hh].w=0.f; }
    const float* vbase = cv + ((size_t)b * 2048 * 8 + kv) * 128
                            + (size_t)s0 * 1024;
    for (int it = 0; it < 16; ++it) {
        float4 vv[4];
        float pp[4][4];
        #pragma unroll
        for (int j = 0; j < 4; ++j) {
            int s = it * 32 + j * 8 + grp;
            vv[j] = *(const float4*)&vbase[(size_t)s * 1024 + d4];
        }
        #pragma unroll
        for (int j = 0; j < 4; ++j) {
            int s = it * 32 + j * 8 + grp;
            #pragma unroll
            for (int hh = 0; hh < 4; ++hh) pp[j][hh] = sbuf[hh * 520 + s];
        }
        #pragma unroll
        for (int j = 0; j < 4; ++j) {
            #pragma unroll
            for (int hh = 0; hh < 4; ++hh) {
                acc[hh].x += pp[j][hh] * vv[j].x;
                acc[hh].y += pp[j][hh] * vv[j].y;
                acc[hh].z += pp[j][hh] * vv[j].z;
                acc[hh].w += pp[j][hh] * vv[j].w;
            }
        }
    }
    if (c == 3 && grp == 0) {
        const float* vr = qkv + (size_t)b * 6144 + 5120 + kv * 128;
        float4 v = *(const float4*)&vr[d4];
        #pragma unroll
        for (int hh = 0; hh < 4; ++hh) {
            float p = sbuf[hh * 520 + 512];
            acc[hh].x += p * v.x; acc[hh].y += p * v.y;
            acc[hh].z += p * v.z; acc[hh].w += p * v.w;
        }
    }
    __syncthreads();   // sc reads done; sbuf becomes op[8][512]

    #pragma unroll
    for (int hh = 0; hh < 4; ++hh)
        *(float4*)&sbuf[grp * 512 + hh * 128 + d4] = acc[hh];
    __syncthreads();

    float* rec = pa + (size_t)blk * 520;
    for (int t = tid; t < 512; t += 256) {
        int hh = t >> 7, d = t & 127;
        float v = 0.f;
        #pragma unroll
        for (int g = 0; g < 8; ++g) v += sbuf[g * 512 + hh * 128 + d];
        rec[8 + hh * 128 + d] = v;
    }
    if (tid < 4) { rec[tid] = pm[tid]; rec[4 + tid] = pl[tid]; }
}

// ---------------------------------------------------------------------------
// Combine 4 flash partials per (b,kv). grid 256, block 128 (= d).
// ---------------------------------------------------------------------------
__global__ __launch_bounds__(128) void attn_combine(
    const float* __restrict__ pa, float* __restrict__ ao)
{
    __shared__ float w_[4][4];   // [c][h] = exp(m_c - M) / L
    const int g = blockIdx.x;
    const int d = threadIdx.x;
    const float* rec = pa + (size_t)g * 4 * 520;

    if (d < 4) {
        float m0 = rec[0*520 + d], m1 = rec[1*520 + d];
        float m2 = rec[2*520 + d], m3 = rec[3*520 + d];
        float M = fmaxf(fmaxf(m0, m1), fmaxf(m2, m3));
        float e0 = __expf(m0 - M), e1 = __expf(m1 - M);
        float e2 = __expf(m2 - M), e3 = __expf(m3 - M);
        float L = rec[0*520 + 4 + d] * e0 + rec[1*520 + 4 + d] * e1
                + rec[2*520 + 4 + d] * e2 + rec[3*520 + 4 + d] * e3;
        float inv = 1.0f / L;
        w_[0][d] = e0 * inv; w_[1][d] = e1 * inv;
        w_[2][d] = e2 * inv; w_[3][d] = e3 * inv;
    }
    __syncthreads();

    #pragma unroll
    for (int h = 0; h < 4; ++h) {
        float v = 0.f;
        #pragma unroll
        for (int c = 0; c < 4; ++c)
            v += rec[c*520 + 8 + h*128 + d] * w_[c][h];
        ao[(size_t)g * 512 + h * 128 + d] = v;
    }
}

// ---------------------------------------------------------------------------
// Reduce 16 split-K partials for output projection -> d_out
// ---------------------------------------------------------------------------
__global__ __launch_bounds__(128) void reduce_out(
    const float* __restrict__ P, float* __restrict__ out)
{
    int t = blockIdx.x * 128 + threadIdx.x;   // float2 units
    int b = t >> 11;
    int cp = t & 2047;
    int n = cp * 2;
    float sx = 0.f, sy = 0.f;
    #pragma unroll
    for (int ks = 0; ks < 16; ++ks) {
        float2 v = *(const float2*)&P[((size_t)ks * 32 + b) * 4096 + n];
        sx += v.x; sy += v.y;
    }
    float2 o; o.x = sx; o.y = sy;
    *(float2*)&out[(size_t)b * 4096 + n] = o;
}

extern "C" void kernel_launch(void* const* d_in, const int* in_sizes, int n_in,
                              void* d_out, int out_size, void* d_ws, size_t ws_size,
                              hipStream_t stream) {
    const float* x  = (const float*)d_in[0];
    const float* wq = (const float*)d_in[1];
    const float* wk = (const float*)d_in[2];
    const float* wv = (const float*)d_in[3];
    const float* wo = (const float*)d_in[4];
    const float* ck = (const float*)d_in[5];
    const float* cv = (const float*)d_in[6];
    const float* fr = (const float*)d_in[7];
    float* out = (float*)d_out;
    float* ws  = (float*)d_ws;

    float* P1   = ws + WS_P1;
    float* PA   = ws + WS_PA;    // aliases P1 (dead after reduce_rope)
    float* qkv  = ws + WS_QKV;
    float* attn = ws + WS_ATTN;
    float* P2   = ws + WS_P2;

    dim3 g1(48, 16);
    gemm_skinny<<<g1, 256, 0, stream>>>(x, wq, 4096, 4096, wk, 5120, 1024,
                                        wv, 1024, P1, 6144);
    reduce_rope<<<768, 128, 0, stream>>>(P1, fr, qkv);
    attn_split<<<1024, 256, 0, stream>>>(qkv, ck, cv, PA);
    attn_combine<<<256, 128, 0, stream>>>(PA, attn);
    dim3 g4(32, 16);
    gemm_skinny<<<g4, 256, 0, stream>>>(attn, wo, 4096, 4096, wo, 4096, 4096,
                                        wo, 4096, P2, 4096);
    reduce_out<<<512, 128, 0, stream>>>(P2, out);
}

// Round 7
// 234.178 us; speedup vs baseline: 1.4231x; 1.4231x over previous
//
#include <hip/hip_runtime.h>

// Shapes: B=32, S_NEW=1, DIM=4096, H=32, KV=8, HD=128, PREV=2048, SEQ=2049
// All inputs/outputs fp32.
//
// ws layout (float offsets):
//   P1   [32][32][6144] @ 0        (6291456) qkv split-K partials
//   PA   [1024][520]    @ 0        (532480)  flash partials (ALIASES dead P1)
//   qkv  [32][6144]     @ 6291456  (196608)  rope'd q (scaled), k_new, v_new
//   attn [32][4096]     @ 6488064  (131072)  attention output (b, h, d)
//   P2   [32][32][4096] @ 6619136  (4194304) out-proj split-K partials

#define WS_P1   0
#define WS_PA   0
#define WS_QKV  6291456
#define WS_ATTN 6488064
#define WS_P2   6619136

// ---------------------------------------------------------------------------
// Skinny GEMM partial (round-3 proven version): P[ks][b][n] over 128-k chunk.
// grid: (Ntot/256, 32), block: 256 threads = 128 colpairs x 2 k-groups.
// ---------------------------------------------------------------------------
__global__ __launch_bounds__(256) void gemm_skinny(
    const float* __restrict__ X,
    const float* __restrict__ W0, int e0, int ld0,
    const float* __restrict__ W1, int e1, int ld1,
    const float* __restrict__ W2, int ld2,
    float* __restrict__ P, int Ntot)
{
    __shared__ float x_t[128][36];     // transposed x chunk [kk][b], pad 36
    __shared__ float2 red[128][33];    // 2-way kg reduce, pad 33

    const int nb = blockIdx.x * 256;
    const float* W; int ld, noff;
    if (nb < e0)      { W = W0; ld = ld0; noff = 0;  }
    else if (nb < e1) { W = W1; ld = ld1; noff = e0; }
    else              { W = W2; ld = ld2; noff = e1; }

    const int k0  = blockIdx.y * 128;
    const int tid = threadIdx.x;
    const int cp  = tid & 127;
    const int kg  = tid >> 7;
    const int nn  = nb - noff + cp * 2;

    #pragma unroll
    for (int i = 0; i < 16; ++i) {
        int idx = tid + i * 256;
        int bb = idx >> 7, kk = idx & 127;
        x_t[kk][bb] = X[(size_t)bb * 4096 + k0 + kk];
    }
    __syncthreads();

    float2 acc[32];
    #pragma unroll
    for (int b = 0; b < 32; ++b) { acc[b].x = 0.f; acc[b].y = 0.f; }

    const float* Wp = W + (size_t)k0 * ld + nn;
    for (int kk0 = kg * 64; kk0 < kg * 64 + 64; kk0 += 8) {
        float2 w[8];
        #pragma unroll
        for (int u = 0; u < 8; ++u)
            w[u] = *(const float2*)&Wp[(size_t)(kk0 + u) * ld];
        #pragma unroll
        for (int u = 0; u < 8; ++u) {
            const float* xr = x_t[kk0 + u];
            #pragma unroll
            for (int bq = 0; bq < 8; ++bq) {
                float4 xv = *(const float4*)&xr[bq * 4];
                acc[bq*4+0].x += xv.x * w[u].x; acc[bq*4+0].y += xv.x * w[u].y;
                acc[bq*4+1].x += xv.y * w[u].x; acc[bq*4+1].y += xv.y * w[u].y;
                acc[bq*4+2].x += xv.z * w[u].x; acc[bq*4+2].y += xv.z * w[u].y;
                acc[bq*4+3].x += xv.w * w[u].x; acc[bq*4+3].y += xv.w * w[u].y;
            }
        }
    }

    if (kg == 1) {
        #pragma unroll
        for (int b = 0; b < 32; ++b) red[cp][b] = acc[b];
    }
    __syncthreads();
    if (kg == 0) {
        const int ks = blockIdx.y;
        #pragma unroll
        for (int b = 0; b < 32; ++b) {
            float2 o = red[cp][b];
            float2 v; v.x = acc[b].x + o.x; v.y = acc[b].y + o.y;
            *(float2*)&P[((size_t)ks * 32 + b) * Ntot + nb + cp * 2] = v;
        }
    }
}

// ---------------------------------------------------------------------------
// Reduce 32 split-K partials for QKV + fused RoPE (+ 1/sqrt(128) on q).
// ---------------------------------------------------------------------------
__global__ __launch_bounds__(128) void reduce_rope(
    const float* __restrict__ P, const float* __restrict__ freqs,
    float* __restrict__ qkv)
{
    int t = blockIdx.x * 128 + threadIdx.x;   // 0..98303
    int b = t / 3072;
    int cp = t - b * 3072;
    int n = cp * 2;
    float sx = 0.f, sy = 0.f;
    #pragma unroll
    for (int ks = 0; ks < 32; ++ks) {
        float2 v = *(const float2*)&P[((size_t)ks * 32 + b) * 6144 + n];
        sx += v.x; sy += v.y;
    }
    if (n < 5120) {
        int d = n & 127;
        float fr = freqs[d >> 1];
        float c = cosf(fr), s = sinf(fr);
        float ra = sx * c - sy * s;
        float rb = sx * s + sy * c;
        if (n < 4096) {
            const float sc = 0.08838834764831845f;  // 1/sqrt(128)
            ra *= sc; rb *= sc;
        }
        sx = ra; sy = rb;
    }
    float2 o; o.x = sx; o.y = sy;
    *(float2*)&qkv[(size_t)b * 6144 + n] = o;
}

// ---------------------------------------------------------------------------
// Flash-decode split-S attention. grid 1024 = (b, kv, chunk c of 512 rows),
// block 256. Phase 1: thread-per-(row, head, half-row): 64 q floats in regs,
// 16 independent float4 K loads per row, ONE shfl_xor to combine halves —
// no serial cross-lane chains between load batches.
// ---------------------------------------------------------------------------
__global__ __launch_bounds__(256, 4) void attn_split(
    const float* __restrict__ qkv,
    const float* __restrict__ ck, const float* __restrict__ cv,
    float* __restrict__ pa)
{
    __shared__ float sbuf[4096];   // sc[4][520] (2080) then op[8][512] (4096)
    __shared__ float pm[4], pl[4];

    const int blk = blockIdx.x;
    const int c   = blk & 3;
    const int kv  = (blk >> 2) & 7;
    const int b   = blk >> 5;
    const int tid = threadIdx.x;
    const int wave = tid >> 6, lane = tid & 63;
    const int s0 = c * 512;

    // -------- phase 1 mapping: head=tid&3, half=(tid>>2)&1, rowg=tid>>3 ----
    const int hh4  = tid & 3;
    const int half = (tid >> 2) & 1;
    const int rowg = tid >> 3;          // 0..31

    // q (this head, this half-row) in registers, pre-scaled by 1/sqrt(128)
    float4 qreg[16];
    {
        const float* qb = qkv + (size_t)b * 6144 + kv * 512 + hh4 * 128 + half * 64;
        #pragma unroll
        for (int u = 0; u < 16; ++u) qreg[u] = *(const float4*)&qb[u * 4];
    }

    // new-token score (chunk 3 only): threads 0..7 (4 heads x 2 halves)
    if (c == 3 && tid < 8) {
        const float* kr = qkv + (size_t)b * 6144 + 4096 + kv * 128 + half * 64;
        float p = 0.f;
        #pragma unroll
        for (int u = 0; u < 16; ++u) {
            float4 ka = *(const float4*)&kr[u * 4];
            p += qreg[u].x*ka.x + qreg[u].y*ka.y + qreg[u].z*ka.z + qreg[u].w*ka.w;
        }
        p += __shfl_xor(p, 4);
        if (half == 0) sbuf[hh4 * 520 + 512] = p;
    }

    // phase 1: 16 passes x 32 rows; 2x8-deep independent load batches/row
    const float* kbase = ck + (((size_t)b * 2048 + s0) * 8 + kv) * 128 + half * 64;
    for (int pass = 0; pass < 16; ++pass) {
        const int s = pass * 32 + rowg;
        const float* kr = kbase + (size_t)s * 1024;
        float p = 0.f;
        #pragma unroll
        for (int g2 = 0; g2 < 2; ++g2) {
            float4 ka[8];
            #pragma unroll
            for (int u = 0; u < 8; ++u)
                ka[u] = *(const float4*)&kr[g2 * 32 + u * 4];
            #pragma unroll
            for (int u = 0; u < 8; ++u) {
                float4 qv = qreg[g2 * 8 + u];
                p += qv.x*ka[u].x + qv.y*ka[u].y + qv.z*ka[u].z + qv.w*ka[u].w;
            }
        }
        p += __shfl_xor(p, 4);
        if (half == 0) sbuf[hh4 * 520 + s] = p;
    }
    __syncthreads();

    // -------- partial softmax: wave w owns head w --------
    {
        const int h = wave;
        const int nrow = (c == 3) ? 513 : 512;
        float m = -1e30f;
        for (int s = lane; s < nrow; s += 64) m = fmaxf(m, sbuf[h * 520 + s]);
        #pragma unroll
        for (int off = 1; off < 64; off <<= 1) m = fmaxf(m, __shfl_xor(m, off));
        float sum = 0.f;
        for (int s = lane; s < nrow; s += 64) {
            float p = __expf(sbuf[h * 520 + s] - m);
            sbuf[h * 520 + s] = p;
            sum += p;
        }
        #pragma unroll
        for (int off = 1; off < 64; off <<= 1) sum += __shfl_xor(sum, off);
        if (lane == 0) { pm[h] = m; pl[h] = sum; }
    }
    __syncthreads();

    // -------- phase 2: o_partial = P @ V, 4-deep load batching --------
    const int grp = tid >> 5, l32 = tid & 31, d4 = l32 * 4;
    float4 acc[4];
    #pragma unroll
    for (int hh = 0; hh < 4; ++hh) { acc[hh].x=0.f; acc[hh].y=0.f; acc[hh].z=0.f; acc[hh].w=0.f; }
    const float* vbase = cv + (((size_t)b * 2048 + s0) * 8 + kv) * 128;
    for (int it = 0; it < 16; ++it) {
        float4 vv[4];
        float pp[4][4];
        #pragma unroll
        for (int j = 0; j < 4; ++j) {
            int s = it * 32 + j * 8 + grp;
            vv[j] = *(const float4*)&vbase[(size_t)s * 1024 + d4];
        }
        #pragma unroll
        for (int j = 0; j < 4; ++j) {
            int s = it * 32 + j * 8 + grp;
            #pragma unroll
            for (int hh = 0; hh < 4; ++hh) pp[j][hh] = sbuf[hh * 520 + s];
        }
        #pragma unroll
        for (int j = 0; j < 4; ++j) {
            #pragma unroll
            for (int hh = 0; hh < 4; ++hh) {
                acc[hh].x += pp[j][hh] * vv[j].x;
                acc[hh].y += pp[j][hh] * vv[j].y;
                acc[hh].z += pp[j][hh] * vv[j].z;
                acc[hh].w += pp[j][hh] * vv[j].w;
            }
        }
    }
    if (c == 3 && grp == 0) {
        const float* vr = qkv + (size_t)b * 6144 + 5120 + kv * 128;
        float4 v = *(const float4*)&vr[d4];
        #pragma unroll
        for (int hh = 0; hh < 4; ++hh) {
            float p = sbuf[hh * 520 + 512];
            acc[hh].x += p * v.x; acc[hh].y += p * v.y;
            acc[hh].z += p * v.z; acc[hh].w += p * v.w;
        }
    }
    __syncthreads();   // sc reads done; sbuf becomes op[8][512]

    #pragma unroll
    for (int hh = 0; hh < 4; ++hh)
        *(float4*)&sbuf[grp * 512 + hh * 128 + d4] = acc[hh];
    __syncthreads();

    float* rec = pa + (size_t)blk * 520;
    for (int t = tid; t < 512; t += 256) {
        int hh = t >> 7, d = t & 127;
        float v = 0.f;
        #pragma unroll
        for (int g = 0; g < 8; ++g) v += sbuf[g * 512 + hh * 128 + d];
        rec[8 + hh * 128 + d] = v;
    }
    if (tid < 4) { rec[tid] = pm[tid]; rec[4 + tid] = pl[tid]; }
}

// ---------------------------------------------------------------------------
// Combine 4 flash partials per (b,kv). grid 256, block 128 (= d).
// ---------------------------------------------------------------------------
__global__ __launch_bounds__(128) void attn_combine(
    const float* __restrict__ pa, float* __restrict__ ao)
{
    __shared__ float w_[4][4];   // [c][h] = exp(m_c - M) / L
    const int g = blockIdx.x;
    const int d = threadIdx.x;
    const float* rec = pa + (size_t)g * 4 * 520;

    if (d < 4) {
        float m0 = rec[0*520 + d], m1 = rec[1*520 + d];
        float m2 = rec[2*520 + d], m3 = rec[3*520 + d];
        float M = fmaxf(fmaxf(m0, m1), fmaxf(m2, m3));
        float e0 = __expf(m0 - M), e1 = __expf(m1 - M);
        float e2 = __expf(m2 - M), e3 = __expf(m3 - M);
        float L = rec[0*520 + 4 + d] * e0 + rec[1*520 + 4 + d] * e1
                + rec[2*520 + 4 + d] * e2 + rec[3*520 + 4 + d] * e3;
        float inv = 1.0f / L;
        w_[0][d] = e0 * inv; w_[1][d] = e1 * inv;
        w_[2][d] = e2 * inv; w_[3][d] = e3 * inv;
    }
    __syncthreads();

    #pragma unroll
    for (int h = 0; h < 4; ++h) {
        float v = 0.f;
        #pragma unroll
        for (int c = 0; c < 4; ++c)
            v += rec[c*520 + 8 + h*128 + d] * w_[c][h];
        ao[(size_t)g * 512 + h * 128 + d] = v;
    }
}

// ---------------------------------------------------------------------------
// Reduce 32 split-K partials for output projection -> d_out
// ---------------------------------------------------------------------------
__global__ __launch_bounds__(128) void reduce_out(
    const float* __restrict__ P, float* __restrict__ out)
{
    int t = blockIdx.x * 128 + threadIdx.x;   // float2 units
    int b = t >> 11;
    int cp = t & 2047;
    int n = cp * 2;
    float sx = 0.f, sy = 0.f;
    #pragma unroll
    for (int ks = 0; ks < 32; ++ks) {
        float2 v = *(const float2*)&P[((size_t)ks * 32 + b) * 4096 + n];
        sx += v.x; sy += v.y;
    }
    float2 o; o.x = sx; o.y = sy;
    *(float2*)&out[(size_t)b * 4096 + n] = o;
}

extern "C" void kernel_launch(void* const* d_in, const int* in_sizes, int n_in,
                              void* d_out, int out_size, void* d_ws, size_t ws_size,
                              hipStream_t stream) {
    const float* x  = (const float*)d_in[0];
    const float* wq = (const float*)d_in[1];
    const float* wk = (const float*)d_in[2];
    const float* wv = (const float*)d_in[3];
    const float* wo = (const float*)d_in[4];
    const float* ck = (const float*)d_in[5];
    const float* cv = (const float*)d_in[6];
    const float* fr = (const float*)d_in[7];
    float* out = (float*)d_out;
    float* ws  = (float*)d_ws;

    float* P1   = ws + WS_P1;
    float* PA   = ws + WS_PA;    // aliases P1 (dead after reduce_rope)
    float* qkv  = ws + WS_QKV;
    float* attn = ws + WS_ATTN;
    float* P2   = ws + WS_P2;

    dim3 g1(24, 32);
    gemm_skinny<<<g1, 256, 0, stream>>>(x, wq, 4096, 4096, wk, 5120, 1024,
                                        wv, 1024, P1, 6144);
    reduce_rope<<<768, 128, 0, stream>>>(P1, fr, qkv);
    attn_split<<<1024, 256, 0, stream>>>(qkv, ck, cv, PA);
    attn_combine<<<256, 128, 0, stream>>>(PA, attn);
    dim3 g4(16, 32);
    gemm_skinny<<<g4, 256, 0, stream>>>(attn, wo, 4096, 4096, wo, 4096, 4096,
                                        wo, 4096, P2, 4096);
    reduce_out<<<512, 128, 0, stream>>>(P2, out);
}

// Round 8
// 216.748 us; speedup vs baseline: 1.5376x; 1.0804x over previous
//
#include <hip/hip_runtime.h>

// Shapes: B=32, S_NEW=1, DIM=4096, H=32, KV=8, HD=128, PREV=2048, SEQ=2049
// All inputs/outputs fp32.
//
// ws layout (float offsets):
//   P1   [32][32][6144] @ 0        (6291456) qkv split-K partials
//   PA   [2048][520]    @ 0        (1064960) flash partials (ALIASES dead P1)
//   qkv  [32][6144]     @ 6291456  (196608)  rope'd q (scaled), k_new, v_new
//   attn [32][4096]     @ 6488064  (131072)  attention output (b, h, d)
//   P2   [32][32][4096] @ 6619136  (4194304) out-proj split-K partials

#define WS_P1   0
#define WS_PA   0
#define WS_QKV  6291456
#define WS_ATTN 6488064
#define WS_P2   6619136

// ---------------------------------------------------------------------------
// Skinny GEMM partial (round-3 proven): P[ks][b][n] over 128-k chunk.
// grid: (Ntot/256, 32), block: 256 threads = 128 colpairs x 2 k-groups.
// ---------------------------------------------------------------------------
__global__ __launch_bounds__(256) void gemm_skinny(
    const float* __restrict__ X,
    const float* __restrict__ W0, int e0, int ld0,
    const float* __restrict__ W1, int e1, int ld1,
    const float* __restrict__ W2, int ld2,
    float* __restrict__ P, int Ntot)
{
    __shared__ float x_t[128][36];     // transposed x chunk [kk][b], pad 36
    __shared__ float2 red[128][33];    // 2-way kg reduce, pad 33

    const int nb = blockIdx.x * 256;
    const float* W; int ld, noff;
    if (nb < e0)      { W = W0; ld = ld0; noff = 0;  }
    else if (nb < e1) { W = W1; ld = ld1; noff = e0; }
    else              { W = W2; ld = ld2; noff = e1; }

    const int k0  = blockIdx.y * 128;
    const int tid = threadIdx.x;
    const int cp  = tid & 127;
    const int kg  = tid >> 7;
    const int nn  = nb - noff + cp * 2;

    #pragma unroll
    for (int i = 0; i < 16; ++i) {
        int idx = tid + i * 256;
        int bb = idx >> 7, kk = idx & 127;
        x_t[kk][bb] = X[(size_t)bb * 4096 + k0 + kk];
    }
    __syncthreads();

    float2 acc[32];
    #pragma unroll
    for (int b = 0; b < 32; ++b) { acc[b].x = 0.f; acc[b].y = 0.f; }

    const float* Wp = W + (size_t)k0 * ld + nn;
    for (int kk0 = kg * 64; kk0 < kg * 64 + 64; kk0 += 8) {
        float2 w[8];
        #pragma unroll
        for (int u = 0; u < 8; ++u)
            w[u] = *(const float2*)&Wp[(size_t)(kk0 + u) * ld];
        #pragma unroll
        for (int u = 0; u < 8; ++u) {
            const float* xr = x_t[kk0 + u];
            #pragma unroll
            for (int bq = 0; bq < 8; ++bq) {
                float4 xv = *(const float4*)&xr[bq * 4];
                acc[bq*4+0].x += xv.x * w[u].x; acc[bq*4+0].y += xv.x * w[u].y;
                acc[bq*4+1].x += xv.y * w[u].x; acc[bq*4+1].y += xv.y * w[u].y;
                acc[bq*4+2].x += xv.z * w[u].x; acc[bq*4+2].y += xv.z * w[u].y;
                acc[bq*4+3].x += xv.w * w[u].x; acc[bq*4+3].y += xv.w * w[u].y;
            }
        }
    }

    if (kg == 1) {
        #pragma unroll
        for (int b = 0; b < 32; ++b) red[cp][b] = acc[b];
    }
    __syncthreads();
    if (kg == 0) {
        const int ks = blockIdx.y;
        #pragma unroll
        for (int b = 0; b < 32; ++b) {
            float2 o = red[cp][b];
            float2 v; v.x = acc[b].x + o.x; v.y = acc[b].y + o.y;
            *(float2*)&P[((size_t)ks * 32 + b) * Ntot + nb + cp * 2] = v;
        }
    }
}

// ---------------------------------------------------------------------------
// Reduce 32 split-K partials for QKV + fused RoPE (+ 1/sqrt(128) on q).
// ---------------------------------------------------------------------------
__global__ __launch_bounds__(128) void reduce_rope(
    const float* __restrict__ P, const float* __restrict__ freqs,
    float* __restrict__ qkv)
{
    int t = blockIdx.x * 128 + threadIdx.x;   // 0..98303
    int b = t / 3072;
    int cp = t - b * 3072;
    int n = cp * 2;
    float sx = 0.f, sy = 0.f;
    #pragma unroll
    for (int ks = 0; ks < 32; ++ks) {
        float2 v = *(const float2*)&P[((size_t)ks * 32 + b) * 6144 + n];
        sx += v.x; sy += v.y;
    }
    if (n < 5120) {
        int d = n & 127;
        float fr = freqs[d >> 1];
        float c = cosf(fr), s = sinf(fr);
        float ra = sx * c - sy * s;
        float rb = sx * s + sy * c;
        if (n < 4096) {
            const float sc = 0.08838834764831845f;  // 1/sqrt(128)
            ra *= sc; rb *= sc;
        }
        sx = ra; sy = rb;
    }
    float2 o; o.x = sx; o.y = sy;
    *(float2*)&qkv[(size_t)b * 6144 + n] = o;
}

// ---------------------------------------------------------------------------
// Flash-decode split-S attention, round-4 coalesced structure, 8 chunks of
// 256 rows. grid 2048 = (b, kv, chunk), block 256, 8 blocks/CU (occupancy).
// Phase 1: 16 lanes x 8 floats = full 1KB K-rows per wave instr, 4-deep.
// Chunk 7 also handles the new token (row 256).
// ---------------------------------------------------------------------------
__global__ __launch_bounds__(256, 8) void attn_split(
    const float* __restrict__ qkv,
    const float* __restrict__ ck, const float* __restrict__ cv,
    float* __restrict__ pa)
{
    __shared__ float sbuf[4096];   // sc[4][260] (1040) then op[8][512] (4096)
    __shared__ float pm[4], pl[4];

    const int blk = blockIdx.x;
    const int c   = blk & 7;
    const int kv  = (blk >> 3) & 7;
    const int b   = blk >> 6;
    const int tid = threadIdx.x;
    const int wave = tid >> 6, lane = tid & 63;
    const int psub = (lane >> 4) & 3, dl = lane & 15;
    const int s0 = c * 256;
    const bool last = (c == 7);

    // q fragments: 4 heads x this lane's 8-dim slice (pre-scaled)
    float q[4][8];
    {
        const float* qb = qkv + (size_t)b * 6144 + kv * 512 + dl * 8;
        #pragma unroll
        for (int h = 0; h < 4; ++h) {
            float4 a = *(const float4*)&qb[h * 128];
            float4 e = *(const float4*)&qb[h * 128 + 4];
            q[h][0]=a.x; q[h][1]=a.y; q[h][2]=a.z; q[h][3]=a.w;
            q[h][4]=e.x; q[h][5]=e.y; q[h][6]=e.z; q[h][7]=e.w;
        }
    }

    // new-token score (chunk 7 only), lanes 0..15
    if (last && tid < 16) {
        const float* kr = qkv + (size_t)b * 6144 + 4096 + kv * 128 + dl * 8;
        float4 k0 = *(const float4*)kr;
        float4 k1 = *(const float4*)(kr + 4);
        float p[4];
        #pragma unroll
        for (int h = 0; h < 4; ++h) {
            p[h] = q[h][0]*k0.x + q[h][1]*k0.y + q[h][2]*k0.z + q[h][3]*k0.w
                 + q[h][4]*k1.x + q[h][5]*k1.y + q[h][6]*k1.z + q[h][7]*k1.w;
        }
        #pragma unroll
        for (int off = 1; off < 16; off <<= 1) {
            #pragma unroll
            for (int h = 0; h < 4; ++h) p[h] += __shfl_xor(p[h], off);
        }
        if (dl == 0) {
            #pragma unroll
            for (int h = 0; h < 4; ++h) sbuf[h * 260 + 256] = p[h];
        }
    }

    // phase 1: scores for this chunk's 256 rows, 4-deep batching
    const float* kbase = ck + (((size_t)b * 2048 + s0) * 8 + kv) * 128;
    const int srow = wave * 4 + psub;       // 0..15
    for (int it0 = 0; it0 < 16; it0 += 4) {
        float4 kA[4][2];
        #pragma unroll
        for (int u = 0; u < 4; ++u) {
            const float* kr = kbase + (size_t)((it0 + u) * 16 + srow) * 1024 + dl * 8;
            kA[u][0] = *(const float4*)kr;
            kA[u][1] = *(const float4*)(kr + 4);
        }
        #pragma unroll
        for (int u = 0; u < 4; ++u) {
            int s = (it0 + u) * 16 + srow;
            float p[4];
            #pragma unroll
            for (int h = 0; h < 4; ++h) {
                p[h] = q[h][0]*kA[u][0].x + q[h][1]*kA[u][0].y
                     + q[h][2]*kA[u][0].z + q[h][3]*kA[u][0].w
                     + q[h][4]*kA[u][1].x + q[h][5]*kA[u][1].y
                     + q[h][6]*kA[u][1].z + q[h][7]*kA[u][1].w;
            }
            #pragma unroll
            for (int off = 1; off < 16; off <<= 1) {
                #pragma unroll
                for (int h = 0; h < 4; ++h) p[h] += __shfl_xor(p[h], off);
            }
            if (dl == 0) {
                #pragma unroll
                for (int h = 0; h < 4; ++h) sbuf[h * 260 + s] = p[h];
            }
        }
    }
    __syncthreads();

    // partial softmax: wave w owns head w
    {
        const int h = wave;
        const int nrow = last ? 257 : 256;
        float m = -1e30f;
        for (int s = lane; s < nrow; s += 64) m = fmaxf(m, sbuf[h * 260 + s]);
        #pragma unroll
        for (int off = 1; off < 64; off <<= 1) m = fmaxf(m, __shfl_xor(m, off));
        float sum = 0.f;
        for (int s = lane; s < nrow; s += 64) {
            float p = __expf(sbuf[h * 260 + s] - m);
            sbuf[h * 260 + s] = p;
            sum += p;
        }
        #pragma unroll
        for (int off = 1; off < 64; off <<= 1) sum += __shfl_xor(sum, off);
        if (lane == 0) { pm[h] = m; pl[h] = sum; }
    }
    __syncthreads();

    // phase 2: o_partial = P @ V over this chunk, 4-deep batching
    const int grp = tid >> 5, l32 = tid & 31, d4 = l32 * 4;
    float4 acc[4];
    #pragma unroll
    for (int hh = 0; hh < 4; ++hh) { acc[hh].x=0.f; acc[hh].y=0.f; acc[hh].z=0.f; acc[hh].w=0.f; }
    const float* vbase = cv + (((size_t)b * 2048 + s0) * 8 + kv) * 128;
    for (int it = 0; it < 8; ++it) {
        float4 vv[4];
        float pp[4][4];
        #pragma unroll
        for (int j = 0; j < 4; ++j) {
            int s = it * 32 + j * 8 + grp;
            vv[j] = *(const float4*)&vbase[(size_t)s * 1024 + d4];
        }
        #pragma unroll
        for (int j = 0; j < 4; ++j) {
            int s = it * 32 + j * 8 + grp;
            #pragma unroll
            for (int hh = 0; hh < 4; ++hh) pp[j][hh] = sbuf[hh * 260 + s];
        }
        #pragma unroll
        for (int j = 0; j < 4; ++j) {
            #pragma unroll
            for (int hh = 0; hh < 4; ++hh) {
                acc[hh].x += pp[j][hh] * vv[j].x;
                acc[hh].y += pp[j][hh] * vv[j].y;
                acc[hh].z += pp[j][hh] * vv[j].z;
                acc[hh].w += pp[j][hh] * vv[j].w;
            }
        }
    }
    if (last && grp == 0) {
        const float* vr = qkv + (size_t)b * 6144 + 5120 + kv * 128;
        float4 v = *(const float4*)&vr[d4];
        #pragma unroll
        for (int hh = 0; hh < 4; ++hh) {
            float p = sbuf[hh * 260 + 256];
            acc[hh].x += p * v.x; acc[hh].y += p * v.y;
            acc[hh].z += p * v.z; acc[hh].w += p * v.w;
        }
    }
    __syncthreads();   // sc reads done; sbuf becomes op[8][512]

    #pragma unroll
    for (int hh = 0; hh < 4; ++hh)
        *(float4*)&sbuf[grp * 512 + hh * 128 + d4] = acc[hh];
    __syncthreads();

    float* rec = pa + (size_t)blk * 520;
    for (int t = tid; t < 512; t += 256) {
        int hh = t >> 7, d = t & 127;
        float v = 0.f;
        #pragma unroll
        for (int g = 0; g < 8; ++g) v += sbuf[g * 512 + hh * 128 + d];
        rec[8 + hh * 128 + d] = v;
    }
    if (tid < 4) { rec[tid] = pm[tid]; rec[4 + tid] = pl[tid]; }
}

// ---------------------------------------------------------------------------
// Combine 8 flash partials per (b,kv). grid 256, block 128 (= d).
// ---------------------------------------------------------------------------
__global__ __launch_bounds__(128) void attn_combine(
    const float* __restrict__ pa, float* __restrict__ ao)
{
    __shared__ float w_[8][4];   // [c][h] = exp(m_c - M) / L
    const int g = blockIdx.x;
    const int b = g >> 3, kv = g & 7;
    const int d = threadIdx.x;
    const float* base = pa + (size_t)(b * 64 + kv * 8) * 520;

    if (d < 4) {
        float M = -1e30f;
        #pragma unroll
        for (int c = 0; c < 8; ++c)
            M = fmaxf(M, base[(size_t)c * 520 + d]);
        float L = 0.f;
        float e[8];
        #pragma unroll
        for (int c = 0; c < 8; ++c) {
            e[c] = __expf(base[(size_t)c * 520 + d] - M);
            L += base[(size_t)c * 520 + 4 + d] * e[c];
        }
        float inv = 1.0f / L;
        #pragma unroll
        for (int c = 0; c < 8; ++c) w_[c][d] = e[c] * inv;
    }
    __syncthreads();

    #pragma unroll
    for (int h = 0; h < 4; ++h) {
        float v = 0.f;
        #pragma unroll
        for (int c = 0; c < 8; ++c)
            v += base[(size_t)c * 520 + 8 + h * 128 + d] * w_[c][h];
        ao[(size_t)g * 512 + h * 128 + d] = v;
    }
}

// ---------------------------------------------------------------------------
// Reduce 32 split-K partials for output projection -> d_out
// ---------------------------------------------------------------------------
__global__ __launch_bounds__(128) void reduce_out(
    const float* __restrict__ P, float* __restrict__ out)
{
    int t = blockIdx.x * 128 + threadIdx.x;   // float2 units
    int b = t >> 11;
    int cp = t & 2047;
    int n = cp * 2;
    float sx = 0.f, sy = 0.f;
    #pragma unroll
    for (int ks = 0; ks < 32; ++ks) {
        float2 v = *(const float2*)&P[((size_t)ks * 32 + b) * 4096 + n];
        sx += v.x; sy += v.y;
    }
    float2 o; o.x = sx; o.y = sy;
    *(float2*)&out[(size_t)b * 4096 + n] = o;
}

extern "C" void kernel_launch(void* const* d_in, const int* in_sizes, int n_in,
                              void* d_out, int out_size, void* d_ws, size_t ws_size,
                              hipStream_t stream) {
    const float* x  = (const float*)d_in[0];
    const float* wq = (const float*)d_in[1];
    const float* wk = (const float*)d_in[2];
    const float* wv = (const float*)d_in[3];
    const float* wo = (const float*)d_in[4];
    const float* ck = (const float*)d_in[5];
    const float* cv = (const float*)d_in[6];
    const float* fr = (const float*)d_in[7];
    float* out = (float*)d_out;
    float* ws  = (float*)d_ws;

    float* P1   = ws + WS_P1;
    float* PA   = ws + WS_PA;    // aliases P1 (dead after reduce_rope)
    float* qkv  = ws + WS_QKV;
    float* attn = ws + WS_ATTN;
    float* P2   = ws + WS_P2;

    dim3 g1(24, 32);
    gemm_skinny<<<g1, 256, 0, stream>>>(x, wq, 4096, 4096, wk, 5120, 1024,
                                        wv, 1024, P1, 6144);
    reduce_rope<<<768, 128, 0, stream>>>(P1, fr, qkv);
    attn_split<<<2048, 256, 0, stream>>>(qkv, ck, cv, PA);
    attn_combine<<<256, 128, 0, stream>>>(PA, attn);
    dim3 g4(16, 32);
    gemm_skinny<<<g4, 256, 0, stream>>>(attn, wo, 4096, 4096, wo, 4096, 4096,
                                        wo, 4096, P2, 4096);
    reduce_out<<<512, 128, 0, stream>>>(P2, out);
}

// Round 9
// 207.286 us; speedup vs baseline: 1.6078x; 1.0456x over previous
//
#include <hip/hip_runtime.h>

// Shapes: B=32, S_NEW=1, DIM=4096, H=32, KV=8, HD=128, PREV=2048, SEQ=2049
// All inputs/outputs fp32.
//
// ws layout (float offsets):
//   P1   [32][32][6144] @ 0         (6291456) qkv split-K partials
//   qkv  [32][6144]     @ 6291456   (196608)  rope'd q (scaled), k_new, v_new
//   attn [32][4096]     @ 6488064   (131072)  attention output (b, h, d)
//   P2   [32][32][4096] @ 6619136   (4194304) out-proj split-K partials
//   SC   [256][2052][4] @ 10813440  (2101248) scores / exp'd probs
//   LINV [256][4]       @ 12914688  (1024)    1/L per (b,kv,h)
//   PA   [2048][512]    @ 12915712  (1048576) pv partials

#define WS_P1   0
#define WS_QKV  6291456
#define WS_ATTN 6488064
#define WS_P2   6619136
#define WS_SC   10813440
#define WS_LINV 12914688
#define WS_PA   12915712

// ---------------------------------------------------------------------------
// Skinny GEMM partial (round-3 proven): P[ks][b][n] over 128-k chunk.
// grid: (Ntot/256, 32), block: 256 threads = 128 colpairs x 2 k-groups.
// ---------------------------------------------------------------------------
__global__ __launch_bounds__(256) void gemm_skinny(
    const float* __restrict__ X,
    const float* __restrict__ W0, int e0, int ld0,
    const float* __restrict__ W1, int e1, int ld1,
    const float* __restrict__ W2, int ld2,
    float* __restrict__ P, int Ntot)
{
    __shared__ float x_t[128][36];     // transposed x chunk [kk][b], pad 36
    __shared__ float2 red[128][33];    // 2-way kg reduce, pad 33

    const int nb = blockIdx.x * 256;
    const float* W; int ld, noff;
    if (nb < e0)      { W = W0; ld = ld0; noff = 0;  }
    else if (nb < e1) { W = W1; ld = ld1; noff = e0; }
    else              { W = W2; ld = ld2; noff = e1; }

    const int k0  = blockIdx.y * 128;
    const int tid = threadIdx.x;
    const int cp  = tid & 127;
    const int kg  = tid >> 7;
    const int nn  = nb - noff + cp * 2;

    #pragma unroll
    for (int i = 0; i < 16; ++i) {
        int idx = tid + i * 256;
        int bb = idx >> 7, kk = idx & 127;
        x_t[kk][bb] = X[(size_t)bb * 4096 + k0 + kk];
    }
    __syncthreads();

    float2 acc[32];
    #pragma unroll
    for (int b = 0; b < 32; ++b) { acc[b].x = 0.f; acc[b].y = 0.f; }

    const float* Wp = W + (size_t)k0 * ld + nn;
    for (int kk0 = kg * 64; kk0 < kg * 64 + 64; kk0 += 8) {
        float2 w[8];
        #pragma unroll
        for (int u = 0; u < 8; ++u)
            w[u] = *(const float2*)&Wp[(size_t)(kk0 + u) * ld];
        #pragma unroll
        for (int u = 0; u < 8; ++u) {
            const float* xr = x_t[kk0 + u];
            #pragma unroll
            for (int bq = 0; bq < 8; ++bq) {
                float4 xv = *(const float4*)&xr[bq * 4];
                acc[bq*4+0].x += xv.x * w[u].x; acc[bq*4+0].y += xv.x * w[u].y;
                acc[bq*4+1].x += xv.y * w[u].x; acc[bq*4+1].y += xv.y * w[u].y;
                acc[bq*4+2].x += xv.z * w[u].x; acc[bq*4+2].y += xv.z * w[u].y;
                acc[bq*4+3].x += xv.w * w[u].x; acc[bq*4+3].y += xv.w * w[u].y;
            }
        }
    }

    if (kg == 1) {
        #pragma unroll
        for (int b = 0; b < 32; ++b) red[cp][b] = acc[b];
    }
    __syncthreads();
    if (kg == 0) {
        const int ks = blockIdx.y;
        #pragma unroll
        for (int b = 0; b < 32; ++b) {
            float2 o = red[cp][b];
            float2 v; v.x = acc[b].x + o.x; v.y = acc[b].y + o.y;
            *(float2*)&P[((size_t)ks * 32 + b) * Ntot + nb + cp * 2] = v;
        }
    }
}

// ---------------------------------------------------------------------------
// Reduce 32 split-K partials for QKV + fused RoPE (+ 1/sqrt(128) on q).
// ---------------------------------------------------------------------------
__global__ __launch_bounds__(128) void reduce_rope(
    const float* __restrict__ P, const float* __restrict__ freqs,
    float* __restrict__ qkv)
{
    int t = blockIdx.x * 128 + threadIdx.x;   // 0..98303
    int b = t / 3072;
    int cp = t - b * 3072;
    int n = cp * 2;
    float sx = 0.f, sy = 0.f;
    #pragma unroll
    for (int ks = 0; ks < 32; ++ks) {
        float2 v = *(const float2*)&P[((size_t)ks * 32 + b) * 6144 + n];
        sx += v.x; sy += v.y;
    }
    if (n < 5120) {
        int d = n & 127;
        float fr = freqs[d >> 1];
        float c = cosf(fr), s = sinf(fr);
        float ra = sx * c - sy * s;
        float rb = sx * s + sy * c;
        if (n < 4096) {
            const float sc = 0.08838834764831845f;  // 1/sqrt(128)
            ra *= sc; rb *= sc;
        }
        sx = ra; sy = rb;
    }
    float2 o; o.x = sx; o.y = sy;
    *(float2*)&qkv[(size_t)b * 6144 + n] = o;
}

// ---------------------------------------------------------------------------
// Scores: pure K-stream, no LDS, no barriers. grid 4096 = (b, kv, chunk of
// 128 rows), block 256. 16 lanes x 8 floats per 512B K-row, 2-deep batch.
// Writes sc[(b*8+kv)][s][4] (stride 4 floats, 16B-aligned float4).
// Chunk 15 also computes the new-token score (s = 2048).
// ---------------------------------------------------------------------------
__global__ __launch_bounds__(256) void attn_scores(
    const float* __restrict__ qkv,
    const float* __restrict__ ck,
    float* __restrict__ sc)
{
    const int blk = blockIdx.x;
    const int c   = blk & 15;
    const int kv  = (blk >> 4) & 7;
    const int b   = blk >> 7;
    const int tid = threadIdx.x;
    const int wave = tid >> 6, lane = tid & 63;
    const int psub = (lane >> 4) & 3, dl = lane & 15;
    const int s0 = c * 128;

    // q: 4 heads x this lane's 8-dim slice (pre-scaled by 1/sqrt(128))
    float q[4][8];
    {
        const float* qb = qkv + (size_t)b * 6144 + kv * 512 + dl * 8;
        #pragma unroll
        for (int h = 0; h < 4; ++h) {
            float4 a = *(const float4*)&qb[h * 128];
            float4 e = *(const float4*)&qb[h * 128 + 4];
            q[h][0]=a.x; q[h][1]=a.y; q[h][2]=a.z; q[h][3]=a.w;
            q[h][4]=e.x; q[h][5]=e.y; q[h][6]=e.z; q[h][7]=e.w;
        }
    }

    float* scb = sc + (size_t)(b * 8 + kv) * 8208;
    const float* kbase = ck + (((size_t)b * 2048 + s0) * 8 + kv) * 128;
    const int srow = wave * 4 + psub;       // 0..15

    for (int it0 = 0; it0 < 8; it0 += 2) {
        float4 kA[2][2];
        #pragma unroll
        for (int u = 0; u < 2; ++u) {
            const float* kr = kbase + (size_t)((it0 + u) * 16 + srow) * 1024 + dl * 8;
            kA[u][0] = *(const float4*)kr;
            kA[u][1] = *(const float4*)(kr + 4);
        }
        #pragma unroll
        for (int u = 0; u < 2; ++u) {
            float p[4];
            #pragma unroll
            for (int h = 0; h < 4; ++h) {
                p[h] = q[h][0]*kA[u][0].x + q[h][1]*kA[u][0].y
                     + q[h][2]*kA[u][0].z + q[h][3]*kA[u][0].w
                     + q[h][4]*kA[u][1].x + q[h][5]*kA[u][1].y
                     + q[h][6]*kA[u][1].z + q[h][7]*kA[u][1].w;
            }
            #pragma unroll
            for (int off = 1; off < 16; off <<= 1) {
                #pragma unroll
                for (int h = 0; h < 4; ++h) p[h] += __shfl_xor(p[h], off);
            }
            if (dl == 0) {
                int s = s0 + (it0 + u) * 16 + srow;
                float4 o; o.x = p[0]; o.y = p[1]; o.z = p[2]; o.w = p[3];
                *(float4*)&scb[(size_t)s * 4] = o;
            }
        }
    }

    // new-token score, chunk 15, lanes 0..15 of wave 0
    if (c == 15 && wave == 0 && psub == 0) {
        const float* kr = qkv + (size_t)b * 6144 + 4096 + kv * 128 + dl * 8;
        float4 k0 = *(const float4*)kr;
        float4 k1 = *(const float4*)(kr + 4);
        float p[4];
        #pragma unroll
        for (int h = 0; h < 4; ++h) {
            p[h] = q[h][0]*k0.x + q[h][1]*k0.y + q[h][2]*k0.z + q[h][3]*k0.w
                 + q[h][4]*k1.x + q[h][5]*k1.y + q[h][6]*k1.z + q[h][7]*k1.w;
        }
        #pragma unroll
        for (int off = 1; off < 16; off <<= 1) {
            #pragma unroll
            for (int h = 0; h < 4; ++h) p[h] += __shfl_xor(p[h], off);
        }
        if (dl == 0) {
            float4 o; o.x = p[0]; o.y = p[1]; o.z = p[2]; o.w = p[3];
            *(float4*)&scb[(size_t)2048 * 4] = o;
        }
    }
}

// ---------------------------------------------------------------------------
// Softmax over full 2049 rows per (b,kv), 4 heads at once (float4 lanes).
// Stores unnormalized exp back to sc and 1/L to linv. grid 256 x 256.
// ---------------------------------------------------------------------------
__global__ __launch_bounds__(256) void attn_softmax(
    float* __restrict__ sc, float* __restrict__ linv)
{
    __shared__ float red[4][4];   // [wave][h]
    const int g = blockIdx.x;
    float* scb = sc + (size_t)g * 8208;
    const int tid = threadIdx.x;
    const int wave = tid >> 6, lane = tid & 63;

    float4 m4; m4.x = -1e30f; m4.y = -1e30f; m4.z = -1e30f; m4.w = -1e30f;
    for (int s = tid; s < 2049; s += 256) {
        float4 v = *(const float4*)&scb[(size_t)s * 4];
        m4.x = fmaxf(m4.x, v.x); m4.y = fmaxf(m4.y, v.y);
        m4.z = fmaxf(m4.z, v.z); m4.w = fmaxf(m4.w, v.w);
    }
    #pragma unroll
    for (int off = 1; off < 64; off <<= 1) {
        m4.x = fmaxf(m4.x, __shfl_xor(m4.x, off));
        m4.y = fmaxf(m4.y, __shfl_xor(m4.y, off));
        m4.z = fmaxf(m4.z, __shfl_xor(m4.z, off));
        m4.w = fmaxf(m4.w, __shfl_xor(m4.w, off));
    }
    if (lane == 0) {
        red[wave][0] = m4.x; red[wave][1] = m4.y;
        red[wave][2] = m4.z; red[wave][3] = m4.w;
    }
    __syncthreads();
    float4 M;
    M.x = fmaxf(fmaxf(red[0][0], red[1][0]), fmaxf(red[2][0], red[3][0]));
    M.y = fmaxf(fmaxf(red[0][1], red[1][1]), fmaxf(red[2][1], red[3][1]));
    M.z = fmaxf(fmaxf(red[0][2], red[1][2]), fmaxf(red[2][2], red[3][2]));
    M.w = fmaxf(fmaxf(red[0][3], red[1][3]), fmaxf(red[2][3], red[3][3]));
    __syncthreads();

    float4 l4; l4.x = 0.f; l4.y = 0.f; l4.z = 0.f; l4.w = 0.f;
    for (int s = tid; s < 2049; s += 256) {
        float4 v = *(const float4*)&scb[(size_t)s * 4];
        v.x = __expf(v.x - M.x); v.y = __expf(v.y - M.y);
        v.z = __expf(v.z - M.z); v.w = __expf(v.w - M.w);
        *(float4*)&scb[(size_t)s * 4] = v;
        l4.x += v.x; l4.y += v.y; l4.z += v.z; l4.w += v.w;
    }
    #pragma unroll
    for (int off = 1; off < 64; off <<= 1) {
        l4.x += __shfl_xor(l4.x, off);
        l4.y += __shfl_xor(l4.y, off);
        l4.z += __shfl_xor(l4.z, off);
        l4.w += __shfl_xor(l4.w, off);
    }
    if (lane == 0) {
        red[wave][0] = l4.x; red[wave][1] = l4.y;
        red[wave][2] = l4.z; red[wave][3] = l4.w;
    }
    __syncthreads();
    if (tid < 4) {
        float L = red[0][tid] + red[1][tid] + red[2][tid] + red[3][tid];
        linv[(size_t)g * 4 + tid] = 1.0f / L;
    }
}

// ---------------------------------------------------------------------------
// PV: pure V-stream, barrier-free main loop. grid 2048 = (b, kv, chunk of
// 256 rows), block 256 = 8 groups of 32 lanes (each group: full 512B V-row).
// Emits normalized partial o[4][128] to PA[blk]. Chunk 7 adds new token.
// ---------------------------------------------------------------------------
__global__ __launch_bounds__(256) void attn_pv(
    const float* __restrict__ qkv, const float* __restrict__ cv,
    const float* __restrict__ sc, const float* __restrict__ linv,
    float* __restrict__ pa)
{
    __shared__ float sbuf[8][512];
    const int blk = blockIdx.x;
    const int c   = blk & 7;
    const int kv  = (blk >> 3) & 7;
    const int b   = blk >> 6;
    const int tid = threadIdx.x;
    const int grp = tid >> 5, l32 = tid & 31, d4 = l32 * 4;
    const int s0 = c * 256;

    const float* scb = sc + (size_t)(b * 8 + kv) * 8208;
    const float* vbase = cv + (((size_t)b * 2048 + s0) * 8 + kv) * 128;

    float4 acc[4];
    #pragma unroll
    for (int h = 0; h < 4; ++h) { acc[h].x=0.f; acc[h].y=0.f; acc[h].z=0.f; acc[h].w=0.f; }

    for (int it = 0; it < 8; ++it) {
        float4 vv[4];
        float4 pj[4];
        #pragma unroll
        for (int j = 0; j < 4; ++j) {
            int sl = it * 32 + j * 8 + grp;
            vv[j] = *(const float4*)&vbase[(size_t)sl * 1024 + d4];
        }
        #pragma unroll
        for (int j = 0; j < 4; ++j) {
            int sl = it * 32 + j * 8 + grp;
            pj[j] = *(const float4*)&scb[(size_t)(s0 + sl) * 4];
        }
        #pragma unroll
        for (int j = 0; j < 4; ++j) {
            acc[0].x += pj[j].x * vv[j].x; acc[0].y += pj[j].x * vv[j].y;
            acc[0].z += pj[j].x * vv[j].z; acc[0].w += pj[j].x * vv[j].w;
            acc[1].x += pj[j].y * vv[j].x; acc[1].y += pj[j].y * vv[j].y;
            acc[1].z += pj[j].y * vv[j].z; acc[1].w += pj[j].y * vv[j].w;
            acc[2].x += pj[j].z * vv[j].x; acc[2].y += pj[j].z * vv[j].y;
            acc[2].z += pj[j].z * vv[j].z; acc[2].w += pj[j].z * vv[j].w;
            acc[3].x += pj[j].w * vv[j].x; acc[3].y += pj[j].w * vv[j].y;
            acc[3].z += pj[j].w * vv[j].z; acc[3].w += pj[j].w * vv[j].w;
        }
    }
    if (c == 7 && grp == 0) {
        const float* vr = qkv + (size_t)b * 6144 + 5120 + kv * 128;
        float4 v = *(const float4*)&vr[d4];
        float4 p = *(const float4*)&scb[(size_t)2048 * 4];
        acc[0].x += p.x * v.x; acc[0].y += p.x * v.y; acc[0].z += p.x * v.z; acc[0].w += p.x * v.w;
        acc[1].x += p.y * v.x; acc[1].y += p.y * v.y; acc[1].z += p.y * v.z; acc[1].w += p.y * v.w;
        acc[2].x += p.z * v.x; acc[2].y += p.z * v.y; acc[2].z += p.z * v.z; acc[2].w += p.z * v.w;
        acc[3].x += p.w * v.x; acc[3].y += p.w * v.y; acc[3].z += p.w * v.z; acc[3].w += p.w * v.w;
    }

    // normalize (compile-time head index), stage, cross-group reduce
    {
        float4 li = *(const float4*)&linv[(size_t)(b * 8 + kv) * 4];
        acc[0].x *= li.x; acc[0].y *= li.x; acc[0].z *= li.x; acc[0].w *= li.x;
        acc[1].x *= li.y; acc[1].y *= li.y; acc[1].z *= li.y; acc[1].w *= li.y;
        acc[2].x *= li.z; acc[2].y *= li.z; acc[2].z *= li.z; acc[2].w *= li.z;
        acc[3].x *= li.w; acc[3].y *= li.w; acc[3].z *= li.w; acc[3].w *= li.w;
    }
    #pragma unroll
    for (int h = 0; h < 4; ++h)
        *(float4*)&sbuf[grp][h * 128 + d4] = acc[h];
    __syncthreads();

    float* rec = pa + (size_t)blk * 512;
    for (int t = tid; t < 512; t += 256) {
        float v = 0.f;
        #pragma unroll
        for (int g2 = 0; g2 < 8; ++g2) v += sbuf[g2][t];
        rec[t] = v;
    }
}

// ---------------------------------------------------------------------------
// Combine 8 normalized PV partials per (b,kv): plain sum. grid 256 x 128.
// ---------------------------------------------------------------------------
__global__ __launch_bounds__(128) void attn_combine(
    const float* __restrict__ pa, float* __restrict__ ao)
{
    const int g = blockIdx.x;   // b*8+kv
    const int d = threadIdx.x;
    const float* base = pa + (size_t)g * 8 * 512;
    #pragma unroll
    for (int h = 0; h < 4; ++h) {
        float v = 0.f;
        #pragma unroll
        for (int c = 0; c < 8; ++c) v += base[c * 512 + h * 128 + d];
        ao[(size_t)(g >> 3) * 4096 + (g & 7) * 512 + h * 128 + d] = v;
    }
}

// ---------------------------------------------------------------------------
// Reduce 32 split-K partials for output projection -> d_out
// ---------------------------------------------------------------------------
__global__ __launch_bounds__(128) void reduce_out(
    const float* __restrict__ P, float* __restrict__ out)
{
    int t = blockIdx.x * 128 + threadIdx.x;   // float2 units
    int b = t >> 11;
    int cp = t & 2047;
    int n = cp * 2;
    float sx = 0.f, sy = 0.f;
    #pragma unroll
    for (int ks = 0; ks < 32; ++ks) {
        float2 v = *(const float2*)&P[((size_t)ks * 32 + b) * 4096 + n];
        sx += v.x; sy += v.y;
    }
    float2 o; o.x = sx; o.y = sy;
    *(float2*)&out[(size_t)b * 4096 + n] = o;
}

extern "C" void kernel_launch(void* const* d_in, const int* in_sizes, int n_in,
                              void* d_out, int out_size, void* d_ws, size_t ws_size,
                              hipStream_t stream) {
    const float* x  = (const float*)d_in[0];
    const float* wq = (const float*)d_in[1];
    const float* wk = (const float*)d_in[2];
    const float* wv = (const float*)d_in[3];
    const float* wo = (const float*)d_in[4];
    const float* ck = (const float*)d_in[5];
    const float* cv = (const float*)d_in[6];
    const float* fr = (const float*)d_in[7];
    float* out = (float*)d_out;
    float* ws  = (float*)d_ws;

    float* P1   = ws + WS_P1;
    float* qkv  = ws + WS_QKV;
    float* attn = ws + WS_ATTN;
    float* P2   = ws + WS_P2;
    float* SC   = ws + WS_SC;
    float* LINV = ws + WS_LINV;
    float* PA   = ws + WS_PA;

    dim3 g1(24, 32);
    gemm_skinny<<<g1, 256, 0, stream>>>(x, wq, 4096, 4096, wk, 5120, 1024,
                                        wv, 1024, P1, 6144);
    reduce_rope<<<768, 128, 0, stream>>>(P1, fr, qkv);
    attn_scores<<<4096, 256, 0, stream>>>(qkv, ck, SC);
    attn_softmax<<<256, 256, 0, stream>>>(SC, LINV);
    attn_pv<<<2048, 256, 0, stream>>>(qkv, cv, SC, LINV, PA);
    attn_combine<<<256, 128, 0, stream>>>(PA, attn);
    dim3 g4(16, 32);
    gemm_skinny<<<g4, 256, 0, stream>>>(attn, wo, 4096, 4096, wo, 4096, 4096,
                                        wo, 4096, P2, 4096);
    reduce_out<<<512, 128, 0, stream>>>(P2, out);
}